// Round 5
// baseline (103.702 us; speedup 1.0000x reference)
//
#include <hip/hip_runtime.h>

// AbsolutePositionExtractor: features[b, s*4 + {0..3}] =
//   [sin(rad_lat*2^s), cos(rad_lat*2^s), sin(rad_lon*2^s), cos(rad_lon*2^s)]
// rad = fl32(deg * fl32(pi/180)); scale_s = int32(2**s) -> JAX int32 wrap:
// s=31 -> -2^31 (sign flip), s>=32 -> 0 -> (sin,cos)=(0,1). mask+positions = 0.
//
// Streaming-store bound (~524 MB). Unit u in [0, B*16): b=u>>4, sp=u&15.
// Each unit writes 4 float4s: computed scales sp and sp+16, constant (0,1,0,1)
// for sp+32 and sp+48. 4 independent stores/iter for MLP; y = rad_d/(2pi)
// hoisted per point; per-scale chain is ldexp(exact) -> floor -> sub -> cvt.
// Plain (L2-buffered) stores: the harness fill kernel hits 87% peak this way;
// nt stores measured slower (R3: 66%).

typedef float f32x4 __attribute__((ext_vector_type(4)));

__device__ __forceinline__ float2 sincos_rev(double v) {
    double f = v - floor(v);            // frac -> revolutions in [0,1)
    float r = (float)f;
    float2 sc;
    sc.x = __builtin_amdgcn_sinf(r);    // v_sin_f32: sin(2*pi*r)
    sc.y = __builtin_amdgcn_cosf(r);    // v_cos_f32
    return sc;
}

__global__ __launch_bounds__(256) void posfeat_kernel(const float* __restrict__ ll,
                                                      f32x4* __restrict__ out,
                                                      int B, long long n4) {
    const double QHI = 0x1.45F306DC9C883p-3;      // fl64(1/(2*pi))
    const float DEG2RAD = 0.017453292519943295f;  // fl32(pi/180), matches np/jax deg2rad

    const long long featUnits = (long long)B * 16;
    const long long stride = (long long)gridDim.x * 256;
    const long long tid0 = (long long)blockIdx.x * 256 + threadIdx.x;
    const f32x4 CONST4 = {0.f, 1.f, 0.f, 1.f};
    const f32x4 ZERO4 = {0.f, 0.f, 0.f, 0.f};

    for (long long u = tid0; u < featUnits; u += stride) {
        int b = (int)(u >> 4);
        int sp = (int)(u & 15);                       // s0 = sp, s1 = sp+16
        float2 p = reinterpret_cast<const float2*>(ll)[b];
        float rlat = p.x * DEG2RAD;                   // single f32 mul — bit-identical to ref
        float rlon = p.y * DEG2RAD;
        double ya = (double)rlat * QHI;               // revolutions at scale 2^0
        double yb = (double)rlon * QHI;

        // s0 = sp in [0,16): scale 2^sp, positive
        float2 a0 = sincos_rev(ldexp(ya, sp));
        float2 b0 = sincos_rev(ldexp(yb, sp));
        // s1 = sp+16 in [16,32): int32 wrap makes s=31 scale -2^31 -> negate
        int s1 = sp + 16;
        double va = ldexp(ya, s1), vb = ldexp(yb, s1);
        if (s1 == 31) { va = -va; vb = -vb; }
        float2 a1 = sincos_rev(va);
        float2 b1 = sincos_rev(vb);

        f32x4 o0 = {a0.x, a0.y, b0.x, b0.y};
        f32x4 o1 = {a1.x, a1.y, b1.x, b1.y};

        long long base = ((long long)b << 6) + sp;
        out[base]      = o0;         // scale sp
        out[base + 16] = o1;         // scale sp+16
        out[base + 32] = CONST4;     // scale sp+32: 2^s==0 -> (0,1,0,1)
        out[base + 48] = CONST4;     // scale sp+48
    }

    // zero tail: mask [B] + positions [2B] as f32, after B*64 float4s of features
    const long long zstart = (long long)B * 64;
    for (long long z = zstart + tid0; z < n4; z += stride) {
        out[z] = ZERO4;
    }
}

__global__ void tail_zero_kernel(float* __restrict__ z, int n) {
    int t = threadIdx.x;
    if (t < n) z[t] = 0.f;
}

extern "C" void kernel_launch(void* const* d_in, const int* in_sizes, int n_in,
                              void* d_out, int out_size, void* d_ws, size_t ws_size,
                              hipStream_t stream) {
    const float* ll = (const float*)d_in[0];
    float* out = (float*)d_out;
    int B = in_sizes[0] / 2;

    long long n4 = (long long)out_size >> 2;
    posfeat_kernel<<<4096, 256, 0, stream>>>(ll, (f32x4*)out, B, n4);

    int tail = out_size & 3;
    if (tail) {
        tail_zero_kernel<<<1, 64, 0, stream>>>(out + ((long long)out_size - tail), tail);
    }
}